// Round 6
// baseline (185.421 us; speedup 1.0000x reference)
//
#include <hip/hip_runtime.h>
#include <stdint.h>

#define N_FEAT 32
#define SCAN_T 1024
#define NXCD 8

// ---------- fallback path (baseline, known-correct, 177us) ----------
__global__ void zero_out(float* __restrict__ out, int n) {
    int i = blockIdx.x * blockDim.x + threadIdx.x;
    if (i < n) out[i] = 0.0f;
}

__global__ void mp_scatter_add(const float* __restrict__ x,
                               const int* __restrict__ src,
                               const int* __restrict__ dst,
                               float* __restrict__ out,
                               int n_edges) {
    long long tid = (long long)blockIdx.x * blockDim.x + threadIdx.x;
    long long total = (long long)n_edges * N_FEAT;
    if (tid >= total) return;
    int e = (int)(tid >> 5);
    int f = (int)(tid & 31);
    atomicAdd(&out[(long long)dst[e] * N_FEAT + f],
              x[(long long)src[e] * N_FEAT + f]);
}

// ---------- fast path: counting-sort by destination node ----------

// K1: per-node histogram. dst is streamed once, no reuse -> NT load.
__global__ void hist_node(const int* __restrict__ dst, int n_edges,
                          int* __restrict__ hist) {
    int stride = gridDim.x * blockDim.x;
    for (int i = blockIdx.x * blockDim.x + threadIdx.x; i < n_edges; i += stride)
        atomicAdd(&hist[__builtin_nontemporal_load(&dst[i])], 1);
}

// K2a: per-block inclusive scan of hist chunk -> offsets[idx+1] (local), block sums.
__global__ void scan_local(const int* __restrict__ hist, int n,
                           int* __restrict__ offsets, int* __restrict__ bsum) {
    __shared__ int s[SCAN_T];
    int idx = blockIdx.x * SCAN_T + threadIdx.x;
    int v = (idx < n) ? hist[idx] : 0;
    s[threadIdx.x] = v;
    __syncthreads();
    for (int off = 1; off < SCAN_T; off <<= 1) {
        int t = (threadIdx.x >= off) ? s[threadIdx.x - off] : 0;
        __syncthreads();
        s[threadIdx.x] += t;
        __syncthreads();
    }
    if (idx < n) offsets[idx + 1] = s[threadIdx.x];
    if (threadIdx.x == SCAN_T - 1) bsum[blockIdx.x] = s[SCAN_T - 1];
}

// K2b: single-block exclusive scan of the <=1024 block sums.
__global__ void scan_bsum(const int* __restrict__ bsum, int* __restrict__ bofs,
                          int nb, int* __restrict__ offsets) {
    __shared__ int s[SCAN_T];
    int t = threadIdx.x;
    int v = (t < nb) ? bsum[t] : 0;
    s[t] = v;
    __syncthreads();
    for (int off = 1; off < SCAN_T; off <<= 1) {
        int u = (t >= off) ? s[t - off] : 0;
        __syncthreads();
        s[t] += u;
        __syncthreads();
    }
    if (t < nb) bofs[t] = s[t] - v;          // exclusive
    if (t == 0) offsets[0] = 0;
}

// K2c: add block offsets; derive per-node start cursor.
__global__ void scan_fix(const int* __restrict__ hist, int n,
                         int* __restrict__ offsets, const int* __restrict__ bofs,
                         int* __restrict__ cursor) {
    int idx = blockIdx.x * SCAN_T + threadIdx.x;
    if (idx < n) {
        int incl = offsets[idx + 1] + bofs[blockIdx.x];
        offsets[idx + 1] = incl;
        cursor[idx] = incl - hist[idx];      // exclusive start of node idx
    }
}

// K3: XCD-cohort scatter with NON-TEMPORAL index reads.
// Cohort c (blockIdx&7) handles dst range c only, so all stores to a given
// 64B line of `sorted` come from one XCD's L2. The NT loads stream dst/src
// past L2, so the cohort's 800KB sorted region + 50KB cursors stay resident
// and partial lines are NOT evicted between the ~16 writes they receive ->
// stores merge, each line written back once.
__global__ void scatter_xcd(const int* __restrict__ src, const int* __restrict__ dst,
                            int n_edges, int n_nodes,
                            int* __restrict__ cursor, uint32_t* __restrict__ sorted) {
    const int xcd = blockIdx.x & (NXCD - 1);
    const int cb  = blockIdx.x >> 3;                 // block index within cohort
    const int CB  = gridDim.x >> 3;                  // blocks per cohort
    const int rng = (n_nodes + NXCD - 1) / NXCD;
    const int rlo = xcd * rng;
    const int rhi = min(rlo + rng, n_nodes);
    const int stride = CB * blockDim.x;
    for (int i = cb * blockDim.x + threadIdx.x; i < n_edges; i += stride) {
        int d = __builtin_nontemporal_load(&dst[i]);
        int s = __builtin_nontemporal_load(&src[i]);  // unconditional: keep coalesced
        if (d >= rlo && d < rhi) {
            int pos = atomicAdd(&cursor[d], 1);
            sorted[pos] = (uint32_t)s;                // normal store: must merge in L2
        }
    }
}

// K4: one 32-lane group per node, float4 lanes.
// Group layout: 4 edge-slots (e4) x 8 feature-quads (q). Each instruction
// gathers 4 full 128B rows per group; ILP-4 puts 16 edges in flight.
// Masked-FMA accumulate, shfl_xor reduce across slots, 8 lanes store the row.
__global__ void __launch_bounds__(256)
aggregate_f4(const float* __restrict__ x,
             const uint32_t* __restrict__ sorted,
             const int* __restrict__ offsets,
             float* __restrict__ out, int n_nodes) {
    int tid = blockIdx.x * blockDim.x + threadIdx.x;
    int g = tid >> 5;                  // node id (32 lanes per node)
    if (g >= n_nodes) return;
    int l  = tid & 31;
    int e4 = l >> 3;                   // edge slot 0..3
    int q  = l & 7;                    // feature quad 0..7
    const float4* __restrict__ x4 = (const float4*)x;

    int beg = offsets[g];
    int end = offsets[g + 1];
    float4 acc = make_float4(0.f, 0.f, 0.f, 0.f);

    for (int i = beg; i < end; i += 16) {
#pragma unroll
        for (int k = 0; k < 4; ++k) {
            int j = i + k * 4 + e4;
            bool ok = j < end;
            uint32_t s = sorted[ok ? j : i];          // clamp to valid (i < end here)
            float4 v = x4[(size_t)s * (N_FEAT / 4) + q]; // 16B/lane, 128B row per slot
            float m = ok ? 1.0f : 0.0f;
            acc.x = fmaf(v.x, m, acc.x);
            acc.y = fmaf(v.y, m, acc.y);
            acc.z = fmaf(v.z, m, acc.z);
            acc.w = fmaf(v.w, m, acc.w);
        }
    }
    // reduce across the 4 edge slots (xor 8,16 stay inside the 32-lane group)
    acc.x += __shfl_xor(acc.x, 8);  acc.y += __shfl_xor(acc.y, 8);
    acc.z += __shfl_xor(acc.z, 8);  acc.w += __shfl_xor(acc.w, 8);
    acc.x += __shfl_xor(acc.x, 16); acc.y += __shfl_xor(acc.y, 16);
    acc.z += __shfl_xor(acc.z, 16); acc.w += __shfl_xor(acc.w, 16);

    if (e4 == 0)
        ((float4*)out)[(size_t)g * (N_FEAT / 4) + q] = acc;
}

extern "C" void kernel_launch(void* const* d_in, const int* in_sizes, int n_in,
                              void* d_out, int out_size, void* d_ws, size_t ws_size,
                              hipStream_t stream) {
    const float* x   = (const float*)d_in[0];
    const int*   ei  = (const int*)d_in[1];
    float*       out = (float*)d_out;

    const int n_edges = in_sizes[1] / 2;
    const int n_nodes = in_sizes[0] / N_FEAT;
    const int* src = ei;
    const int* dst = ei + n_edges;

    const int nscan = (n_nodes + SCAN_T - 1) / SCAN_T;

    // workspace layout
    size_t off_sorted  = 0;
    size_t off_hist    = off_sorted + (size_t)n_edges * sizeof(uint32_t);
    size_t off_offsets = off_hist + (size_t)n_nodes * sizeof(int);
    size_t off_cursor  = off_offsets + (size_t)(n_nodes + 1) * sizeof(int);
    size_t off_bsum    = off_cursor + (size_t)n_nodes * sizeof(int);
    size_t off_bofs    = off_bsum + (size_t)nscan * sizeof(int);
    size_t ws_needed   = off_bofs + (size_t)nscan * sizeof(int);

    if (nscan > SCAN_T || ws_size < ws_needed) {
        // fallback: baseline atomic scatter (correct, ~177us)
        int threads = 256;
        zero_out<<<(out_size + threads - 1) / threads, threads, 0, stream>>>(out, out_size);
        long long total = (long long)n_edges * N_FEAT;
        mp_scatter_add<<<(int)((total + threads - 1) / threads), threads, 0, stream>>>(
            x, src, dst, out, n_edges);
        return;
    }

    char* ws = (char*)d_ws;
    uint32_t* sorted  = (uint32_t*)(ws + off_sorted);
    int*      hist    = (int*)(ws + off_hist);
    int*      offsets = (int*)(ws + off_offsets);
    int*      cursor  = (int*)(ws + off_cursor);
    int*      bsum    = (int*)(ws + off_bsum);
    int*      bofs    = (int*)(ws + off_bofs);

    hipMemsetAsync(hist, 0, (size_t)n_nodes * sizeof(int), stream);

    hist_node<<<2048, 256, 0, stream>>>(dst, n_edges, hist);
    scan_local<<<nscan, SCAN_T, 0, stream>>>(hist, n_nodes, offsets, bsum);
    scan_bsum<<<1, SCAN_T, 0, stream>>>(bsum, bofs, nscan, offsets);
    scan_fix<<<nscan, SCAN_T, 0, stream>>>(hist, n_nodes, offsets, bofs, cursor);
    scatter_xcd<<<2048, 256, 0, stream>>>(src, dst, n_edges, n_nodes, cursor, sorted);
    aggregate_f4<<<(n_nodes * 32 + 255) / 256, 256, 0, stream>>>(x, sorted, offsets, out, n_nodes);
}

// Round 7
// 162.603 us; speedup vs baseline: 1.1403x; 1.1403x over previous
//
#include <hip/hip_runtime.h>
#include <stdint.h>

#define N_FEAT 32
#define SCAN_T 1024
#define NPB_SHIFT 8                   // 256 nodes per bin (shift, not divide)
#define NPB (1 << NPB_SHIFT)
#define MAX_BINS 512
#define BIN_CAP 8192                  // LDS sort capacity; avg bin ~4096 edges
#define PART_BLOCKS 128

// ---------- fallback path (baseline, known-correct, ~177us) ----------
__global__ void zero_out(float* __restrict__ out, int n) {
    int i = blockIdx.x * blockDim.x + threadIdx.x;
    if (i < n) out[i] = 0.0f;
}

__global__ void mp_scatter_add(const float* __restrict__ x,
                               const int* __restrict__ src,
                               const int* __restrict__ dst,
                               float* __restrict__ out,
                               int n_edges) {
    long long tid = (long long)blockIdx.x * blockDim.x + threadIdx.x;
    long long total = (long long)n_edges * N_FEAT;
    if (tid >= total) return;
    int e = (int)(tid >> 5);
    int f = (int)(tid & 31);
    atomicAdd(&out[(long long)dst[e] * N_FEAT + f],
              x[(long long)src[e] * N_FEAT + f]);
}

// ---------- fast path: CSR build via two-level bin sort ----------

// K1: per-node histogram.
__global__ void hist_node(const int* __restrict__ dst, int n_edges,
                          int* __restrict__ hist) {
    int stride = gridDim.x * blockDim.x;
    for (int i = blockIdx.x * blockDim.x + threadIdx.x; i < n_edges; i += stride)
        atomicAdd(&hist[__builtin_nontemporal_load(&dst[i])], 1);
}

// K2a: per-block inclusive scan of hist chunk -> offsets[idx+1] (local), block sums.
__global__ void scan_local(const int* __restrict__ hist, int n,
                           int* __restrict__ offsets, int* __restrict__ bsum) {
    __shared__ int s[SCAN_T];
    int idx = blockIdx.x * SCAN_T + threadIdx.x;
    int v = (idx < n) ? hist[idx] : 0;
    s[threadIdx.x] = v;
    __syncthreads();
    for (int off = 1; off < SCAN_T; off <<= 1) {
        int t = (threadIdx.x >= off) ? s[threadIdx.x - off] : 0;
        __syncthreads();
        s[threadIdx.x] += t;
        __syncthreads();
    }
    if (idx < n) offsets[idx + 1] = s[threadIdx.x];
    if (threadIdx.x == SCAN_T - 1) bsum[blockIdx.x] = s[SCAN_T - 1];
}

// K2b: single-block exclusive scan of the <=1024 block sums.
__global__ void scan_bsum(const int* __restrict__ bsum, int* __restrict__ bofs,
                          int nb, int* __restrict__ offsets) {
    __shared__ int s[SCAN_T];
    int t = threadIdx.x;
    int v = (t < nb) ? bsum[t] : 0;
    s[t] = v;
    __syncthreads();
    for (int off = 1; off < SCAN_T; off <<= 1) {
        int u = (t >= off) ? s[t - off] : 0;
        __syncthreads();
        s[t] += u;
        __syncthreads();
    }
    if (t < nb) bofs[t] = s[t] - v;          // exclusive
    if (t == 0) offsets[0] = 0;
}

// K2c: add block offsets; also emit per-bin start cursor (= offsets[b*NPB]).
__global__ void scan_fix(const int* __restrict__ hist, int n,
                         int* __restrict__ offsets, const int* __restrict__ bofs,
                         int* __restrict__ bincur) {
    int idx = blockIdx.x * SCAN_T + threadIdx.x;
    if (idx < n) {
        int incl = offsets[idx + 1] + bofs[blockIdx.x];
        offsets[idx + 1] = incl;
        if ((idx & (NPB - 1)) == 0)
            bincur[idx >> NPB_SHIFT] = incl - hist[idx];   // exclusive start of bin
    }
}

// K3: partition edges into 256-node bins. All global writes are to
// block-private per-bin segments (~100B each, 50KB working set per block):
// L2-merges cleanly, each line written back once. One global atomic per
// (block,bin) for the reservation.
__global__ void __launch_bounds__(256)
partition_bins(const int* __restrict__ src, const int* __restrict__ dst,
               int n_edges, int* __restrict__ bincur,
               uint32_t* __restrict__ binstream, int nbins) {
    __shared__ int cnt[MAX_BINS];
    __shared__ int base[MAX_BINS];
    const int chunk = (n_edges + gridDim.x - 1) / gridDim.x;
    const int beg = blockIdx.x * chunk;
    const int end = min(beg + chunk, n_edges);

    for (int b = threadIdx.x; b < nbins; b += blockDim.x) cnt[b] = 0;
    __syncthreads();
    for (int i = beg + threadIdx.x; i < end; i += blockDim.x)
        atomicAdd(&cnt[dst[i] >> NPB_SHIFT], 1);           // LDS atomic
    __syncthreads();
    for (int b = threadIdx.x; b < nbins; b += blockDim.x) {
        int c = cnt[b];
        base[b] = c ? atomicAdd(&bincur[b], c) : 0;        // one global atomic each
        cnt[b] = 0;                                        // becomes local cursor
    }
    __syncthreads();
    for (int i = beg + threadIdx.x; i < end; i += blockDim.x) {
        int d = dst[i];
        int s = src[i];
        int b = d >> NPB_SHIFT;
        int p = base[b] + atomicAdd(&cnt[b], 1);           // LDS atomic
        binstream[p] = ((uint32_t)s << NPB_SHIFT) | (uint32_t)(d & (NPB - 1));
    }
}

// K4: one block per bin. Read bin stream coalesced, place each edge at its
// final rank inside a 32KB LDS buffer (rank = global offsets slice + LDS
// cursor), then stream out fully coalesced. binstream segments for a bin are
// laid out in [offsets[n0], offsets[n1]) because bincur was initialized to
// the bin's CSR start.
__global__ void __launch_bounds__(256)
binsort(const uint32_t* __restrict__ binstream, const int* __restrict__ offsets,
        uint32_t* __restrict__ sorted, int n_nodes) {
    __shared__ uint32_t srtd[BIN_CAP];
    __shared__ int offs[NPB + 1];
    __shared__ int lcur[NPB];
    const int n0 = blockIdx.x << NPB_SHIFT;
    const int nn = min(n0 + NPB, n_nodes) - n0;
    for (int j = threadIdx.x; j <= nn; j += blockDim.x) offs[j] = offsets[n0 + j];
    for (int j = threadIdx.x; j < nn; j += blockDim.x) lcur[j] = 0;
    __syncthreads();
    const int binstart = offs[0];
    const int cnt = offs[nn] - binstart;

    if (cnt <= BIN_CAP) {
        for (int i = threadIdx.x; i < cnt; i += blockDim.x) {
            uint32_t e = binstream[binstart + i];          // coalesced read
            int dl = (int)(e & (NPB - 1));
            int p = (offs[dl] - binstart) + atomicAdd(&lcur[dl], 1);
            srtd[p] = e >> NPB_SHIFT;                      // src id
        }
        __syncthreads();
        for (int i = threadIdx.x; i < cnt; i += blockDim.x)
            sorted[binstart + i] = srtd[i];                // coalesced write
    } else {
        // overflow (>BIN_CAP edges in one bin; ~impossible for random input):
        // correct direct scatter, separate src/dst buffers so no race.
        for (int i = threadIdx.x; i < cnt; i += blockDim.x) {
            uint32_t e = binstream[binstart + i];
            int dl = (int)(e & (NPB - 1));
            int p = offs[dl] + atomicAdd(&lcur[dl], 1);
            sorted[p] = e >> NPB_SHIFT;
        }
    }
}

// K5: one 32-lane group per node, float4 lanes, 16 edges in flight.
__global__ void __launch_bounds__(256)
aggregate_f4(const float* __restrict__ x,
             const uint32_t* __restrict__ sorted,
             const int* __restrict__ offsets,
             float* __restrict__ out, int n_nodes) {
    int tid = blockIdx.x * blockDim.x + threadIdx.x;
    int g = tid >> 5;                  // node id (32 lanes per node)
    if (g >= n_nodes) return;
    int l  = tid & 31;
    int e4 = l >> 3;                   // edge slot 0..3
    int q  = l & 7;                    // feature quad 0..7
    const float4* __restrict__ x4 = (const float4*)x;

    int beg = offsets[g];
    int end = offsets[g + 1];
    float4 acc = make_float4(0.f, 0.f, 0.f, 0.f);

    for (int i = beg; i < end; i += 16) {
#pragma unroll
        for (int k = 0; k < 4; ++k) {
            int j = i + k * 4 + e4;
            bool ok = j < end;
            uint32_t s = sorted[ok ? j : i];              // clamp: i < end here
            float4 v = x4[(size_t)s * (N_FEAT / 4) + q];  // 16B/lane gather
            float m = ok ? 1.0f : 0.0f;
            acc.x = fmaf(v.x, m, acc.x);
            acc.y = fmaf(v.y, m, acc.y);
            acc.z = fmaf(v.z, m, acc.z);
            acc.w = fmaf(v.w, m, acc.w);
        }
    }
    acc.x += __shfl_xor(acc.x, 8);  acc.y += __shfl_xor(acc.y, 8);
    acc.z += __shfl_xor(acc.z, 8);  acc.w += __shfl_xor(acc.w, 8);
    acc.x += __shfl_xor(acc.x, 16); acc.y += __shfl_xor(acc.y, 16);
    acc.z += __shfl_xor(acc.z, 16); acc.w += __shfl_xor(acc.w, 16);

    if (e4 == 0)
        ((float4*)out)[(size_t)g * (N_FEAT / 4) + q] = acc;
}

extern "C" void kernel_launch(void* const* d_in, const int* in_sizes, int n_in,
                              void* d_out, int out_size, void* d_ws, size_t ws_size,
                              hipStream_t stream) {
    const float* x   = (const float*)d_in[0];
    const int*   ei  = (const int*)d_in[1];
    float*       out = (float*)d_out;

    const int n_edges = in_sizes[1] / 2;
    const int n_nodes = in_sizes[0] / N_FEAT;
    const int* src = ei;
    const int* dst = ei + n_edges;

    const int nscan = (n_nodes + SCAN_T - 1) / SCAN_T;
    const int nbins = (n_nodes + NPB - 1) >> NPB_SHIFT;

    // workspace layout
    size_t off_binstream = 0;
    size_t off_sorted    = off_binstream + (size_t)n_edges * sizeof(uint32_t);
    size_t off_hist      = off_sorted + (size_t)n_edges * sizeof(uint32_t);
    size_t off_offsets   = off_hist + (size_t)n_nodes * sizeof(int);
    size_t off_bsum      = off_offsets + (size_t)(n_nodes + 1) * sizeof(int);
    size_t off_bofs      = off_bsum + (size_t)nscan * sizeof(int);
    size_t off_bincur    = off_bofs + (size_t)nscan * sizeof(int);
    size_t ws_needed     = off_bincur + (size_t)nbins * sizeof(int);

    if (nscan > SCAN_T || nbins > MAX_BINS || n_nodes > (1 << 24) ||
        ws_size < ws_needed) {
        // fallback: baseline atomic scatter (correct, ~177us)
        int threads = 256;
        zero_out<<<(out_size + threads - 1) / threads, threads, 0, stream>>>(out, out_size);
        long long total = (long long)n_edges * N_FEAT;
        mp_scatter_add<<<(int)((total + threads - 1) / threads), threads, 0, stream>>>(
            x, src, dst, out, n_edges);
        return;
    }

    char* ws = (char*)d_ws;
    uint32_t* binstream = (uint32_t*)(ws + off_binstream);
    uint32_t* sorted    = (uint32_t*)(ws + off_sorted);
    int*      hist      = (int*)(ws + off_hist);
    int*      offsets   = (int*)(ws + off_offsets);
    int*      bsum      = (int*)(ws + off_bsum);
    int*      bofs      = (int*)(ws + off_bofs);
    int*      bincur    = (int*)(ws + off_bincur);

    hipMemsetAsync(hist, 0, (size_t)n_nodes * sizeof(int), stream);

    hist_node<<<2048, 256, 0, stream>>>(dst, n_edges, hist);
    scan_local<<<nscan, SCAN_T, 0, stream>>>(hist, n_nodes, offsets, bsum);
    scan_bsum<<<1, SCAN_T, 0, stream>>>(bsum, bofs, nscan, offsets);
    scan_fix<<<nscan, SCAN_T, 0, stream>>>(hist, n_nodes, offsets, bofs, bincur);
    partition_bins<<<PART_BLOCKS, 256, 0, stream>>>(src, dst, n_edges, bincur, binstream, nbins);
    binsort<<<nbins, 256, 0, stream>>>(binstream, offsets, sorted, n_nodes);
    aggregate_f4<<<(n_nodes * 32 + 255) / 256, 256, 0, stream>>>(x, sorted, offsets, out, n_nodes);
}

// Round 8
// 113.847 us; speedup vs baseline: 1.6287x; 1.4283x over previous
//
#include <hip/hip_runtime.h>
#include <stdint.h>

#define N_FEAT 32
#define NPB_SHIFT 8                   // 256 nodes per bin
#define NPB (1 << NPB_SHIFT)
#define MAX_BINS 512
#define BIN_CAP 8192                  // LDS sort capacity; avg bin ~4096 edges
#define PART_BLOCKS 128

// ---------- fallback path (baseline, known-correct, ~177us) ----------
__global__ void zero_out(float* __restrict__ out, int n) {
    int i = blockIdx.x * blockDim.x + threadIdx.x;
    if (i < n) out[i] = 0.0f;
}

__global__ void mp_scatter_add(const float* __restrict__ x,
                               const int* __restrict__ src,
                               const int* __restrict__ dst,
                               float* __restrict__ out,
                               int n_edges) {
    long long tid = (long long)blockIdx.x * blockDim.x + threadIdx.x;
    long long total = (long long)n_edges * N_FEAT;
    if (tid >= total) return;
    int e = (int)(tid >> 5);
    int f = (int)(tid & 31);
    atomicAdd(&out[(long long)dst[e] * N_FEAT + f],
              x[(long long)src[e] * N_FEAT + f]);
}

// ---------- fast path ----------
// No per-NODE global histogram anywhere: node-level counting happens in LDS
// inside binsort, which emits its 256-entry slice of the CSR offsets.

// K0: per-BIN histogram (<=512 bins). LDS-aggregated; ~nbins global atomics
// per block on a 1.5KB array -> negligible traffic.
__global__ void bin_hist(const int* __restrict__ dst, int n_edges,
                         int* __restrict__ bincnt, int nbins) {
    __shared__ int lh[MAX_BINS];
    for (int j = threadIdx.x; j < nbins; j += blockDim.x) lh[j] = 0;
    __syncthreads();
    int stride = gridDim.x * blockDim.x;
    for (int i = blockIdx.x * blockDim.x + threadIdx.x; i < n_edges; i += stride)
        atomicAdd(&lh[__builtin_nontemporal_load(&dst[i]) >> NPB_SHIFT], 1);
    __syncthreads();
    for (int j = threadIdx.x; j < nbins; j += blockDim.x) {
        int c = lh[j];
        if (c) atomicAdd(&bincnt[j], c);
    }
}

// K1: single-block exclusive scan of bin counts -> binofs[0..nbins], bincur.
__global__ void bin_scan(const int* __restrict__ bincnt, int nbins,
                         int* __restrict__ binofs, int* __restrict__ bincur) {
    __shared__ int s[MAX_BINS];
    int t = threadIdx.x;                       // blockDim.x == MAX_BINS
    int v = (t < nbins) ? bincnt[t] : 0;
    s[t] = v;
    __syncthreads();
    for (int off = 1; off < MAX_BINS; off <<= 1) {
        int u = (t >= off) ? s[t - off] : 0;
        __syncthreads();
        s[t] += u;
        __syncthreads();
    }
    if (t < nbins) {
        int excl = s[t] - v;
        binofs[t] = excl;
        bincur[t] = excl;
        if (t == nbins - 1) binofs[nbins] = s[t];
    }
}

// K2: partition edges into 256-node bins. All global writes go to
// block-private per-bin segments (~128B each, ~50KB working set per block):
// merge in L2, each line written back once. One global atomic per (block,bin).
__global__ void __launch_bounds__(256)
partition_bins(const int* __restrict__ src, const int* __restrict__ dst,
               int n_edges, int* __restrict__ bincur,
               uint32_t* __restrict__ binstream, int nbins) {
    __shared__ int cnt[MAX_BINS];
    __shared__ int base[MAX_BINS];
    const int chunk = (n_edges + gridDim.x - 1) / gridDim.x;
    const int beg = blockIdx.x * chunk;
    const int end = min(beg + chunk, n_edges);

    for (int b = threadIdx.x; b < nbins; b += blockDim.x) cnt[b] = 0;
    __syncthreads();
    for (int i = beg + threadIdx.x; i < end; i += blockDim.x)
        atomicAdd(&cnt[dst[i] >> NPB_SHIFT], 1);           // LDS atomic
    __syncthreads();
    for (int b = threadIdx.x; b < nbins; b += blockDim.x) {
        int c = cnt[b];
        base[b] = c ? atomicAdd(&bincur[b], c) : 0;        // one global atomic each
        cnt[b] = 0;                                        // becomes local cursor
    }
    __syncthreads();
    for (int i = beg + threadIdx.x; i < end; i += blockDim.x) {
        int d = dst[i];
        int s = src[i];
        int b = d >> NPB_SHIFT;
        int p = base[b] + atomicAdd(&cnt[b], 1);           // LDS atomic
        binstream[p] = ((uint32_t)s << NPB_SHIFT) | (uint32_t)(d & (NPB - 1));
    }
}

// K3: one block per bin. Builds the per-node histogram in LDS, scans it,
// EMITS this bin's slice of the global CSR offsets, then places edges at
// final rank in LDS and streams out fully coalesced.
__global__ void __launch_bounds__(256)
binsort(const uint32_t* __restrict__ binstream, const int* __restrict__ binofs,
        int nbins, uint32_t* __restrict__ sorted, int* __restrict__ offsets,
        int n_nodes) {
    __shared__ uint32_t srtd[BIN_CAP];     // 32 KB
    __shared__ int hist[NPB];              // counts -> (after) exclusive offsets
    __shared__ int sc[NPB];                // scan workspace
    __shared__ int lcur[NPB];
    const int b = blockIdx.x;
    const int n0 = b << NPB_SHIFT;
    const int nn = min(NPB, n_nodes - n0);
    const int binstart = binofs[b];
    const int cnt = binofs[b + 1] - binstart;
    const int t = threadIdx.x;             // blockDim.x == NPB == 256

    hist[t] = 0;
    lcur[t] = 0;
    __syncthreads();

    for (int i = t; i < cnt; i += blockDim.x)
        atomicAdd(&hist[binstream[binstart + i] & (NPB - 1)], 1);
    __syncthreads();

    // inclusive scan of hist into sc
    int v = hist[t];
    sc[t] = v;
    __syncthreads();
    for (int off = 1; off < NPB; off <<= 1) {
        int u = (t >= off) ? sc[t - off] : 0;
        __syncthreads();
        sc[t] += u;
        __syncthreads();
    }
    // emit global CSR offsets for this bin; hist becomes local exclusive offset
    if (t < nn) offsets[n0 + t + 1] = binstart + sc[t];
    if (b == 0 && t == 0) offsets[0] = 0;
    hist[t] = sc[t] - v;                   // exclusive
    __syncthreads();

    if (cnt <= BIN_CAP) {
        for (int i = t; i < cnt; i += blockDim.x) {
            uint32_t e = binstream[binstart + i];          // coalesced read
            int dl = (int)(e & (NPB - 1));
            int p = hist[dl] + atomicAdd(&lcur[dl], 1);
            srtd[p] = e >> NPB_SHIFT;                      // src id
        }
        __syncthreads();
        for (int i = t; i < cnt; i += blockDim.x)
            sorted[binstart + i] = srtd[i];                // coalesced write
    } else {
        // overflow (>BIN_CAP edges in one bin; ~impossible for random input)
        for (int i = t; i < cnt; i += blockDim.x) {
            uint32_t e = binstream[binstart + i];
            int dl = (int)(e & (NPB - 1));
            int p = binstart + hist[dl] + atomicAdd(&lcur[dl], 1);
            sorted[p] = e >> NPB_SHIFT;
        }
    }
}

// K4: one 32-lane group per node, float4 lanes, 16 edges in flight.
__global__ void __launch_bounds__(256)
aggregate_f4(const float* __restrict__ x,
             const uint32_t* __restrict__ sorted,
             const int* __restrict__ offsets,
             float* __restrict__ out, int n_nodes) {
    int tid = blockIdx.x * blockDim.x + threadIdx.x;
    int g = tid >> 5;                  // node id (32 lanes per node)
    if (g >= n_nodes) return;
    int l  = tid & 31;
    int e4 = l >> 3;                   // edge slot 0..3
    int q  = l & 7;                    // feature quad 0..7
    const float4* __restrict__ x4 = (const float4*)x;

    int beg = offsets[g];
    int end = offsets[g + 1];
    float4 acc = make_float4(0.f, 0.f, 0.f, 0.f);

    for (int i = beg; i < end; i += 16) {
#pragma unroll
        for (int k = 0; k < 4; ++k) {
            int j = i + k * 4 + e4;
            bool ok = j < end;
            uint32_t s = sorted[ok ? j : i];              // clamp: i < end here
            float4 v = x4[(size_t)s * (N_FEAT / 4) + q];  // 16B/lane gather
            float m = ok ? 1.0f : 0.0f;
            acc.x = fmaf(v.x, m, acc.x);
            acc.y = fmaf(v.y, m, acc.y);
            acc.z = fmaf(v.z, m, acc.z);
            acc.w = fmaf(v.w, m, acc.w);
        }
    }
    acc.x += __shfl_xor(acc.x, 8);  acc.y += __shfl_xor(acc.y, 8);
    acc.z += __shfl_xor(acc.z, 8);  acc.w += __shfl_xor(acc.w, 8);
    acc.x += __shfl_xor(acc.x, 16); acc.y += __shfl_xor(acc.y, 16);
    acc.z += __shfl_xor(acc.z, 16); acc.w += __shfl_xor(acc.w, 16);

    if (e4 == 0)
        ((float4*)out)[(size_t)g * (N_FEAT / 4) + q] = acc;
}

extern "C" void kernel_launch(void* const* d_in, const int* in_sizes, int n_in,
                              void* d_out, int out_size, void* d_ws, size_t ws_size,
                              hipStream_t stream) {
    const float* x   = (const float*)d_in[0];
    const int*   ei  = (const int*)d_in[1];
    float*       out = (float*)d_out;

    const int n_edges = in_sizes[1] / 2;
    const int n_nodes = in_sizes[0] / N_FEAT;
    const int* src = ei;
    const int* dst = ei + n_edges;

    const int nbins = (n_nodes + NPB - 1) >> NPB_SHIFT;

    // workspace layout
    size_t off_binstream = 0;
    size_t off_sorted    = off_binstream + (size_t)n_edges * sizeof(uint32_t);
    size_t off_offsets   = off_sorted + (size_t)n_edges * sizeof(uint32_t);
    size_t off_bincnt    = off_offsets + (size_t)(n_nodes + 1) * sizeof(int);
    size_t off_binofs    = off_bincnt + (size_t)nbins * sizeof(int);
    size_t off_bincur    = off_binofs + (size_t)(nbins + 1) * sizeof(int);
    size_t ws_needed     = off_bincur + (size_t)nbins * sizeof(int);

    if (nbins > MAX_BINS || n_nodes > (1 << 23) || ws_size < ws_needed) {
        // fallback: baseline atomic scatter (correct, ~177us)
        int threads = 256;
        zero_out<<<(out_size + threads - 1) / threads, threads, 0, stream>>>(out, out_size);
        long long total = (long long)n_edges * N_FEAT;
        mp_scatter_add<<<(int)((total + threads - 1) / threads), threads, 0, stream>>>(
            x, src, dst, out, n_edges);
        return;
    }

    char* ws = (char*)d_ws;
    uint32_t* binstream = (uint32_t*)(ws + off_binstream);
    uint32_t* sorted    = (uint32_t*)(ws + off_sorted);
    int*      offsets   = (int*)(ws + off_offsets);
    int*      bincnt    = (int*)(ws + off_bincnt);
    int*      binofs    = (int*)(ws + off_binofs);
    int*      bincur    = (int*)(ws + off_bincur);

    hipMemsetAsync(bincnt, 0, (size_t)nbins * sizeof(int), stream);

    bin_hist<<<512, 256, 0, stream>>>(dst, n_edges, bincnt, nbins);
    bin_scan<<<1, MAX_BINS, 0, stream>>>(bincnt, nbins, binofs, bincur);
    partition_bins<<<PART_BLOCKS, 256, 0, stream>>>(src, dst, n_edges, bincur, binstream, nbins);
    binsort<<<nbins, NPB, 0, stream>>>(binstream, binofs, nbins, sorted, offsets, n_nodes);
    aggregate_f4<<<(n_nodes * 32 + 255) / 256, 256, 0, stream>>>(x, sorted, offsets, out, n_nodes);
}

// Round 9
// 104.378 us; speedup vs baseline: 1.7764x; 1.0907x over previous
//
#include <hip/hip_runtime.h>
#include <stdint.h>

#define N_FEAT 32
#define NPB_SHIFT 8                   // 256 nodes per bin
#define NPB (1 << NPB_SHIFT)
#define MAX_BINS 512
#define BIN_CAP 8192                  // LDS sort capacity; avg bin ~4096 edges
#define PART_BLOCKS 512               // R8: 128 -> 512. Occupancy 4.8% was the
                                      // partition wall (latency exposure); 32B
                                      // segments still merge ~2:1 in L2.

// ---------- fallback path (baseline, known-correct, ~177us) ----------
__global__ void zero_out(float* __restrict__ out, int n) {
    int i = blockIdx.x * blockDim.x + threadIdx.x;
    if (i < n) out[i] = 0.0f;
}

__global__ void mp_scatter_add(const float* __restrict__ x,
                               const int* __restrict__ src,
                               const int* __restrict__ dst,
                               float* __restrict__ out,
                               int n_edges) {
    long long tid = (long long)blockIdx.x * blockDim.x + threadIdx.x;
    long long total = (long long)n_edges * N_FEAT;
    if (tid >= total) return;
    int e = (int)(tid >> 5);
    int f = (int)(tid & 31);
    atomicAdd(&out[(long long)dst[e] * N_FEAT + f],
              x[(long long)src[e] * N_FEAT + f]);
}

// ---------- fast path ----------

// K0: per-BIN histogram (<=512 bins). LDS-aggregated.
__global__ void bin_hist(const int* __restrict__ dst, int n_edges,
                         int* __restrict__ bincnt, int nbins) {
    __shared__ int lh[MAX_BINS];
    for (int j = threadIdx.x; j < nbins; j += blockDim.x) lh[j] = 0;
    __syncthreads();
    int stride = gridDim.x * blockDim.x;
    for (int i = blockIdx.x * blockDim.x + threadIdx.x; i < n_edges; i += stride)
        atomicAdd(&lh[__builtin_nontemporal_load(&dst[i]) >> NPB_SHIFT], 1);
    __syncthreads();
    for (int j = threadIdx.x; j < nbins; j += blockDim.x) {
        int c = lh[j];
        if (c) atomicAdd(&bincnt[j], c);
    }
}

// K1: single-block exclusive scan of bin counts -> binofs[0..nbins], bincur.
__global__ void bin_scan(const int* __restrict__ bincnt, int nbins,
                         int* __restrict__ binofs, int* __restrict__ bincur) {
    __shared__ int s[MAX_BINS];
    int t = threadIdx.x;                       // blockDim.x == MAX_BINS
    int v = (t < nbins) ? bincnt[t] : 0;
    s[t] = v;
    __syncthreads();
    for (int off = 1; off < MAX_BINS; off <<= 1) {
        int u = (t >= off) ? s[t - off] : 0;
        __syncthreads();
        s[t] += u;
        __syncthreads();
    }
    if (t < nbins) {
        int excl = s[t] - v;
        binofs[t] = excl;
        bincur[t] = excl;
        if (t == nbins - 1) binofs[nbins] = s[t];
    }
}

// K2: partition edges into 256-node bins. Per-(block,bin) segments (~32B at
// 512 blocks) merge ~2:1 in L2; one global reservation atomic per (block,bin).
__global__ void __launch_bounds__(256)
partition_bins(const int* __restrict__ src, const int* __restrict__ dst,
               int n_edges, int* __restrict__ bincur,
               uint32_t* __restrict__ binstream, int nbins) {
    __shared__ int cnt[MAX_BINS];
    __shared__ int base[MAX_BINS];
    const int chunk = (n_edges + gridDim.x - 1) / gridDim.x;
    const int beg = blockIdx.x * chunk;
    const int end = min(beg + chunk, n_edges);

    for (int b = threadIdx.x; b < nbins; b += blockDim.x) cnt[b] = 0;
    __syncthreads();
    for (int i = beg + threadIdx.x; i < end; i += blockDim.x)
        atomicAdd(&cnt[dst[i] >> NPB_SHIFT], 1);           // LDS atomic
    __syncthreads();
    for (int b = threadIdx.x; b < nbins; b += blockDim.x) {
        int c = cnt[b];
        base[b] = c ? atomicAdd(&bincur[b], c) : 0;        // one global atomic each
        cnt[b] = 0;                                        // becomes local cursor
    }
    __syncthreads();
    for (int i = beg + threadIdx.x; i < end; i += blockDim.x) {
        int d = dst[i];
        int s = src[i];
        int b = d >> NPB_SHIFT;
        int p = base[b] + atomicAdd(&cnt[b], 1);           // LDS atomic
        binstream[p] = ((uint32_t)s << NPB_SHIFT) | (uint32_t)(d & (NPB - 1));
    }
}

// K3: one block per bin. Per-node LDS histogram + scan, emits this bin's
// slice of the CSR offsets, places edges at final rank in LDS, streams out
// coalesced.
__global__ void __launch_bounds__(256)
binsort(const uint32_t* __restrict__ binstream, const int* __restrict__ binofs,
        int nbins, uint32_t* __restrict__ sorted, int* __restrict__ offsets,
        int n_nodes) {
    __shared__ uint32_t srtd[BIN_CAP];     // 32 KB
    __shared__ int hist[NPB];              // counts -> (after) exclusive offsets
    __shared__ int sc[NPB];                // scan workspace
    __shared__ int lcur[NPB];
    const int b = blockIdx.x;
    const int n0 = b << NPB_SHIFT;
    const int nn = min(NPB, n_nodes - n0);
    const int binstart = binofs[b];
    const int cnt = binofs[b + 1] - binstart;
    const int t = threadIdx.x;             // blockDim.x == NPB == 256

    hist[t] = 0;
    lcur[t] = 0;
    __syncthreads();

    for (int i = t; i < cnt; i += blockDim.x)
        atomicAdd(&hist[binstream[binstart + i] & (NPB - 1)], 1);
    __syncthreads();

    // inclusive scan of hist into sc
    int v = hist[t];
    sc[t] = v;
    __syncthreads();
    for (int off = 1; off < NPB; off <<= 1) {
        int u = (t >= off) ? sc[t - off] : 0;
        __syncthreads();
        sc[t] += u;
        __syncthreads();
    }
    if (t < nn) offsets[n0 + t + 1] = binstart + sc[t];
    if (b == 0 && t == 0) offsets[0] = 0;
    hist[t] = sc[t] - v;                   // exclusive
    __syncthreads();

    if (cnt <= BIN_CAP) {
        for (int i = t; i < cnt; i += blockDim.x) {
            uint32_t e = binstream[binstart + i];          // coalesced read
            int dl = (int)(e & (NPB - 1));
            int p = hist[dl] + atomicAdd(&lcur[dl], 1);
            srtd[p] = e >> NPB_SHIFT;                      // src id
        }
        __syncthreads();
        for (int i = t; i < cnt; i += blockDim.x)
            sorted[binstart + i] = srtd[i];                // coalesced write
    } else {
        // overflow (>BIN_CAP edges in one bin; ~impossible for random input)
        for (int i = t; i < cnt; i += blockDim.x) {
            uint32_t e = binstream[binstart + i];
            int dl = (int)(e & (NPB - 1));
            int p = binstart + hist[dl] + atomicAdd(&lcur[dl], 1);
            sorted[p] = e >> NPB_SHIFT;
        }
    }
}

// K4: one 32-lane group per node, float4 lanes, 16 edges in flight.
__global__ void __launch_bounds__(256)
aggregate_f4(const float* __restrict__ x,
             const uint32_t* __restrict__ sorted,
             const int* __restrict__ offsets,
             float* __restrict__ out, int n_nodes) {
    int tid = blockIdx.x * blockDim.x + threadIdx.x;
    int g = tid >> 5;                  // node id (32 lanes per node)
    if (g >= n_nodes) return;
    int l  = tid & 31;
    int e4 = l >> 3;                   // edge slot 0..3
    int q  = l & 7;                    // feature quad 0..7
    const float4* __restrict__ x4 = (const float4*)x;

    int beg = offsets[g];
    int end = offsets[g + 1];
    float4 acc = make_float4(0.f, 0.f, 0.f, 0.f);

    for (int i = beg; i < end; i += 16) {
#pragma unroll
        for (int k = 0; k < 4; ++k) {
            int j = i + k * 4 + e4;
            bool ok = j < end;
            uint32_t s = sorted[ok ? j : i];              // clamp: i < end here
            float4 v = x4[(size_t)s * (N_FEAT / 4) + q];  // 16B/lane gather
            float m = ok ? 1.0f : 0.0f;
            acc.x = fmaf(v.x, m, acc.x);
            acc.y = fmaf(v.y, m, acc.y);
            acc.z = fmaf(v.z, m, acc.z);
            acc.w = fmaf(v.w, m, acc.w);
        }
    }
    acc.x += __shfl_xor(acc.x, 8);  acc.y += __shfl_xor(acc.y, 8);
    acc.z += __shfl_xor(acc.z, 8);  acc.w += __shfl_xor(acc.w, 8);
    acc.x += __shfl_xor(acc.x, 16); acc.y += __shfl_xor(acc.y, 16);
    acc.z += __shfl_xor(acc.z, 16); acc.w += __shfl_xor(acc.w, 16);

    if (e4 == 0)
        ((float4*)out)[(size_t)g * (N_FEAT / 4) + q] = acc;
}

extern "C" void kernel_launch(void* const* d_in, const int* in_sizes, int n_in,
                              void* d_out, int out_size, void* d_ws, size_t ws_size,
                              hipStream_t stream) {
    const float* x   = (const float*)d_in[0];
    const int*   ei  = (const int*)d_in[1];
    float*       out = (float*)d_out;

    const int n_edges = in_sizes[1] / 2;
    const int n_nodes = in_sizes[0] / N_FEAT;
    const int* src = ei;
    const int* dst = ei + n_edges;

    const int nbins = (n_nodes + NPB - 1) >> NPB_SHIFT;

    // workspace layout
    size_t off_binstream = 0;
    size_t off_sorted    = off_binstream + (size_t)n_edges * sizeof(uint32_t);
    size_t off_offsets   = off_sorted + (size_t)n_edges * sizeof(uint32_t);
    size_t off_bincnt    = off_offsets + (size_t)(n_nodes + 1) * sizeof(int);
    size_t off_binofs    = off_bincnt + (size_t)nbins * sizeof(int);
    size_t off_bincur    = off_binofs + (size_t)(nbins + 1) * sizeof(int);
    size_t ws_needed     = off_bincur + (size_t)nbins * sizeof(int);

    if (nbins > MAX_BINS || n_nodes > (1 << 23) || ws_size < ws_needed) {
        // fallback: baseline atomic scatter (correct, ~177us)
        int threads = 256;
        zero_out<<<(out_size + threads - 1) / threads, threads, 0, stream>>>(out, out_size);
        long long total = (long long)n_edges * N_FEAT;
        mp_scatter_add<<<(int)((total + threads - 1) / threads), threads, 0, stream>>>(
            x, src, dst, out, n_edges);
        return;
    }

    char* ws = (char*)d_ws;
    uint32_t* binstream = (uint32_t*)(ws + off_binstream);
    uint32_t* sorted    = (uint32_t*)(ws + off_sorted);
    int*      offsets   = (int*)(ws + off_offsets);
    int*      bincnt    = (int*)(ws + off_bincnt);
    int*      binofs    = (int*)(ws + off_binofs);
    int*      bincur    = (int*)(ws + off_bincur);

    hipMemsetAsync(bincnt, 0, (size_t)nbins * sizeof(int), stream);

    bin_hist<<<512, 256, 0, stream>>>(dst, n_edges, bincnt, nbins);
    bin_scan<<<1, MAX_BINS, 0, stream>>>(bincnt, nbins, binofs, bincur);
    partition_bins<<<PART_BLOCKS, 256, 0, stream>>>(src, dst, n_edges, bincur, binstream, nbins);
    binsort<<<nbins, NPB, 0, stream>>>(binstream, binofs, nbins, sorted, offsets, n_nodes);
    aggregate_f4<<<(n_nodes * 32 + 255) / 256, 256, 0, stream>>>(x, sorted, offsets, out, n_nodes);
}

// Round 10
// 99.782 us; speedup vs baseline: 1.8583x; 1.0461x over previous
//
#include <hip/hip_runtime.h>
#include <stdint.h>

#define N_FEAT 32
#define NPB_SHIFT 8                   // 256 nodes per bin
#define NPB (1 << NPB_SHIFT)
#define MAX_BINS 512
#define BIN_CAP 8192                  // LDS sort capacity; avg bin ~4096 edges
#define PART_BLOCKS 512               // R8: occupancy was the partition wall
#define HIST_BLOCKS 256               // R9: partial-hist rows (no memset needed)

// ---------- fallback path (baseline, known-correct, ~177us) ----------
__global__ void zero_out(float* __restrict__ out, int n) {
    int i = blockIdx.x * blockDim.x + threadIdx.x;
    if (i < n) out[i] = 0.0f;
}

__global__ void mp_scatter_add(const float* __restrict__ x,
                               const int* __restrict__ src,
                               const int* __restrict__ dst,
                               float* __restrict__ out,
                               int n_edges) {
    long long tid = (long long)blockIdx.x * blockDim.x + threadIdx.x;
    long long total = (long long)n_edges * N_FEAT;
    if (tid >= total) return;
    int e = (int)(tid >> 5);
    int f = (int)(tid & 31);
    atomicAdd(&out[(long long)dst[e] * N_FEAT + f],
              x[(long long)src[e] * N_FEAT + f]);
}

// ---------- fast path ----------
// R9 change: NO hipMemsetAsync anywhere. bin_hist writes per-block partial
// histograms with plain stores (every slot written each call -> poison-safe,
// replay-deterministic); bin_scan reduces the partials then scans.

// K0: per-block partial bin histogram. partial[blk*MAX_BINS + j] plain store.
__global__ void bin_hist(const int* __restrict__ dst, int n_edges,
                         int* __restrict__ partial, int nbins) {
    __shared__ int lh[MAX_BINS];
    for (int j = threadIdx.x; j < nbins; j += blockDim.x) lh[j] = 0;
    __syncthreads();
    int stride = gridDim.x * blockDim.x;
    for (int i = blockIdx.x * blockDim.x + threadIdx.x; i < n_edges; i += stride)
        atomicAdd(&lh[__builtin_nontemporal_load(&dst[i]) >> NPB_SHIFT], 1);
    __syncthreads();
    for (int j = threadIdx.x; j < nbins; j += blockDim.x)
        partial[blockIdx.x * MAX_BINS + j] = lh[j];        // coalesced store
}

// K1: reduce partials (coalesced rows) + exclusive scan -> binofs, bincur.
__global__ void bin_scan(const int* __restrict__ partial, int nbins,
                         int* __restrict__ binofs, int* __restrict__ bincur) {
    __shared__ int s[MAX_BINS];
    int t = threadIdx.x;                       // blockDim.x == MAX_BINS
    int v = 0;
    if (t < nbins) {
#pragma unroll 8
        for (int k = 0; k < HIST_BLOCKS; ++k)
            v += partial[k * MAX_BINS + t];    // row k: consecutive addresses
    }
    s[t] = v;
    __syncthreads();
    for (int off = 1; off < MAX_BINS; off <<= 1) {
        int u = (t >= off) ? s[t - off] : 0;
        __syncthreads();
        s[t] += u;
        __syncthreads();
    }
    if (t < nbins) {
        int excl = s[t] - v;
        binofs[t] = excl;
        bincur[t] = excl;
        if (t == nbins - 1) binofs[nbins] = s[t];
    }
}

// K2: partition edges into 256-node bins. Per-(block,bin) segments (~32B at
// 512 blocks) merge ~2:1 in L2; one global reservation atomic per (block,bin).
__global__ void __launch_bounds__(256)
partition_bins(const int* __restrict__ src, const int* __restrict__ dst,
               int n_edges, int* __restrict__ bincur,
               uint32_t* __restrict__ binstream, int nbins) {
    __shared__ int cnt[MAX_BINS];
    __shared__ int base[MAX_BINS];
    const int chunk = (n_edges + gridDim.x - 1) / gridDim.x;
    const int beg = blockIdx.x * chunk;
    const int end = min(beg + chunk, n_edges);

    for (int b = threadIdx.x; b < nbins; b += blockDim.x) cnt[b] = 0;
    __syncthreads();
    for (int i = beg + threadIdx.x; i < end; i += blockDim.x)
        atomicAdd(&cnt[dst[i] >> NPB_SHIFT], 1);           // LDS atomic
    __syncthreads();
    for (int b = threadIdx.x; b < nbins; b += blockDim.x) {
        int c = cnt[b];
        base[b] = c ? atomicAdd(&bincur[b], c) : 0;        // one global atomic each
        cnt[b] = 0;                                        // becomes local cursor
    }
    __syncthreads();
    for (int i = beg + threadIdx.x; i < end; i += blockDim.x) {
        int d = dst[i];
        int s = src[i];
        int b = d >> NPB_SHIFT;
        int p = base[b] + atomicAdd(&cnt[b], 1);           // LDS atomic
        binstream[p] = ((uint32_t)s << NPB_SHIFT) | (uint32_t)(d & (NPB - 1));
    }
}

// K3: one block per bin. Per-node LDS histogram + scan, emits this bin's
// slice of the CSR offsets, places edges at final rank in LDS, streams out
// coalesced.
__global__ void __launch_bounds__(256)
binsort(const uint32_t* __restrict__ binstream, const int* __restrict__ binofs,
        int nbins, uint32_t* __restrict__ sorted, int* __restrict__ offsets,
        int n_nodes) {
    __shared__ uint32_t srtd[BIN_CAP];     // 32 KB
    __shared__ int hist[NPB];              // counts -> (after) exclusive offsets
    __shared__ int sc[NPB];                // scan workspace
    __shared__ int lcur[NPB];
    const int b = blockIdx.x;
    const int n0 = b << NPB_SHIFT;
    const int nn = min(NPB, n_nodes - n0);
    const int binstart = binofs[b];
    const int cnt = binofs[b + 1] - binstart;
    const int t = threadIdx.x;             // blockDim.x == NPB == 256

    hist[t] = 0;
    lcur[t] = 0;
    __syncthreads();

    for (int i = t; i < cnt; i += blockDim.x)
        atomicAdd(&hist[binstream[binstart + i] & (NPB - 1)], 1);
    __syncthreads();

    // inclusive scan of hist into sc
    int v = hist[t];
    sc[t] = v;
    __syncthreads();
    for (int off = 1; off < NPB; off <<= 1) {
        int u = (t >= off) ? sc[t - off] : 0;
        __syncthreads();
        sc[t] += u;
        __syncthreads();
    }
    if (t < nn) offsets[n0 + t + 1] = binstart + sc[t];
    if (b == 0 && t == 0) offsets[0] = 0;
    hist[t] = sc[t] - v;                   // exclusive
    __syncthreads();

    if (cnt <= BIN_CAP) {
        for (int i = t; i < cnt; i += blockDim.x) {
            uint32_t e = binstream[binstart + i];          // coalesced read
            int dl = (int)(e & (NPB - 1));
            int p = hist[dl] + atomicAdd(&lcur[dl], 1);
            srtd[p] = e >> NPB_SHIFT;                      // src id
        }
        __syncthreads();
        for (int i = t; i < cnt; i += blockDim.x)
            sorted[binstart + i] = srtd[i];                // coalesced write
    } else {
        // overflow (>BIN_CAP edges in one bin; ~impossible for random input)
        for (int i = t; i < cnt; i += blockDim.x) {
            uint32_t e = binstream[binstart + i];
            int dl = (int)(e & (NPB - 1));
            int p = binstart + hist[dl] + atomicAdd(&lcur[dl], 1);
            sorted[p] = e >> NPB_SHIFT;
        }
    }
}

// K4: one 32-lane group per node, float4 lanes, 16 edges in flight.
__global__ void __launch_bounds__(256)
aggregate_f4(const float* __restrict__ x,
             const uint32_t* __restrict__ sorted,
             const int* __restrict__ offsets,
             float* __restrict__ out, int n_nodes) {
    int tid = blockIdx.x * blockDim.x + threadIdx.x;
    int g = tid >> 5;                  // node id (32 lanes per node)
    if (g >= n_nodes) return;
    int l  = tid & 31;
    int e4 = l >> 3;                   // edge slot 0..3
    int q  = l & 7;                    // feature quad 0..7
    const float4* __restrict__ x4 = (const float4*)x;

    int beg = offsets[g];
    int end = offsets[g + 1];
    float4 acc = make_float4(0.f, 0.f, 0.f, 0.f);

    for (int i = beg; i < end; i += 16) {
#pragma unroll
        for (int k = 0; k < 4; ++k) {
            int j = i + k * 4 + e4;
            bool ok = j < end;
            uint32_t s = sorted[ok ? j : i];              // clamp: i < end here
            float4 v = x4[(size_t)s * (N_FEAT / 4) + q];  // 16B/lane gather
            float m = ok ? 1.0f : 0.0f;
            acc.x = fmaf(v.x, m, acc.x);
            acc.y = fmaf(v.y, m, acc.y);
            acc.z = fmaf(v.z, m, acc.z);
            acc.w = fmaf(v.w, m, acc.w);
        }
    }
    acc.x += __shfl_xor(acc.x, 8);  acc.y += __shfl_xor(acc.y, 8);
    acc.z += __shfl_xor(acc.z, 8);  acc.w += __shfl_xor(acc.w, 8);
    acc.x += __shfl_xor(acc.x, 16); acc.y += __shfl_xor(acc.y, 16);
    acc.z += __shfl_xor(acc.z, 16); acc.w += __shfl_xor(acc.w, 16);

    if (e4 == 0)
        ((float4*)out)[(size_t)g * (N_FEAT / 4) + q] = acc;
}

extern "C" void kernel_launch(void* const* d_in, const int* in_sizes, int n_in,
                              void* d_out, int out_size, void* d_ws, size_t ws_size,
                              hipStream_t stream) {
    const float* x   = (const float*)d_in[0];
    const int*   ei  = (const int*)d_in[1];
    float*       out = (float*)d_out;

    const int n_edges = in_sizes[1] / 2;
    const int n_nodes = in_sizes[0] / N_FEAT;
    const int* src = ei;
    const int* dst = ei + n_edges;

    const int nbins = (n_nodes + NPB - 1) >> NPB_SHIFT;

    // workspace layout
    size_t off_binstream = 0;
    size_t off_sorted    = off_binstream + (size_t)n_edges * sizeof(uint32_t);
    size_t off_offsets   = off_sorted + (size_t)n_edges * sizeof(uint32_t);
    size_t off_partial   = off_offsets + (size_t)(n_nodes + 1) * sizeof(int);
    size_t off_binofs    = off_partial + (size_t)HIST_BLOCKS * MAX_BINS * sizeof(int);
    size_t off_bincur    = off_binofs + (size_t)(nbins + 1) * sizeof(int);
    size_t ws_needed     = off_bincur + (size_t)nbins * sizeof(int);

    if (nbins > MAX_BINS || n_nodes > (1 << 23) || ws_size < ws_needed) {
        // fallback: baseline atomic scatter (correct, ~177us)
        int threads = 256;
        zero_out<<<(out_size + threads - 1) / threads, threads, 0, stream>>>(out, out_size);
        long long total = (long long)n_edges * N_FEAT;
        mp_scatter_add<<<(int)((total + threads - 1) / threads), threads, 0, stream>>>(
            x, src, dst, out, n_edges);
        return;
    }

    char* ws = (char*)d_ws;
    uint32_t* binstream = (uint32_t*)(ws + off_binstream);
    uint32_t* sorted    = (uint32_t*)(ws + off_sorted);
    int*      offsets   = (int*)(ws + off_offsets);
    int*      partial   = (int*)(ws + off_partial);
    int*      binofs    = (int*)(ws + off_binofs);
    int*      bincur    = (int*)(ws + off_bincur);

    bin_hist<<<HIST_BLOCKS, 256, 0, stream>>>(dst, n_edges, partial, nbins);
    bin_scan<<<1, MAX_BINS, 0, stream>>>(partial, nbins, binofs, bincur);
    partition_bins<<<PART_BLOCKS, 256, 0, stream>>>(src, dst, n_edges, bincur, binstream, nbins);
    binsort<<<nbins, NPB, 0, stream>>>(binstream, binofs, nbins, sorted, offsets, n_nodes);
    aggregate_f4<<<(n_nodes * 32 + 255) / 256, 256, 0, stream>>>(x, sorted, offsets, out, n_nodes);
}

// Round 11
// 84.669 us; speedup vs baseline: 2.1900x; 1.1785x over previous
//
#include <hip/hip_runtime.h>
#include <stdint.h>

#define N_FEAT 32
#define NPB_SHIFT 8                   // 256 nodes per bin
#define NPB (1 << NPB_SHIFT)
#define MAX_BINS 512
#define BIN_CAP 8192                  // LDS sort capacity; avg bin ~4096 edges
#define PART_BLOCKS 512               // 2 blocks/CU
#define PART_THREADS 1024             // R10: 16 waves/block -> 32 waves/CU
#define HIST_BLOCKS 256
#define HIST_THREADS 1024
#define SORT_THREADS 1024

// ---------- fallback path (baseline, known-correct, ~177us) ----------
__global__ void zero_out(float* __restrict__ out, int n) {
    int i = blockIdx.x * blockDim.x + threadIdx.x;
    if (i < n) out[i] = 0.0f;
}

__global__ void mp_scatter_add(const float* __restrict__ x,
                               const int* __restrict__ src,
                               const int* __restrict__ dst,
                               float* __restrict__ out,
                               int n_edges) {
    long long tid = (long long)blockIdx.x * blockDim.x + threadIdx.x;
    long long total = (long long)n_edges * N_FEAT;
    if (tid >= total) return;
    int e = (int)(tid >> 5);
    int f = (int)(tid & 31);
    atomicAdd(&out[(long long)dst[e] * N_FEAT + f],
              x[(long long)src[e] * N_FEAT + f]);
}

// ---------- fast path ----------
// No memsets: bin_hist writes per-block partial histograms with plain stores.

// K0: per-block partial bin histogram.
__global__ void __launch_bounds__(HIST_THREADS)
bin_hist(const int* __restrict__ dst, int n_edges,
         int* __restrict__ partial, int nbins) {
    __shared__ int lh[MAX_BINS];
    for (int j = threadIdx.x; j < nbins; j += blockDim.x) lh[j] = 0;
    __syncthreads();
    int stride = gridDim.x * blockDim.x;
    for (int i = blockIdx.x * blockDim.x + threadIdx.x; i < n_edges; i += stride)
        atomicAdd(&lh[__builtin_nontemporal_load(&dst[i]) >> NPB_SHIFT], 1);
    __syncthreads();
    for (int j = threadIdx.x; j < nbins; j += blockDim.x)
        partial[blockIdx.x * MAX_BINS + j] = lh[j];        // coalesced store
}

// K1: reduce partials (coalesced rows) + exclusive scan -> binofs, bincur.
__global__ void bin_scan(const int* __restrict__ partial, int nbins,
                         int* __restrict__ binofs, int* __restrict__ bincur) {
    __shared__ int s[MAX_BINS];
    int t = threadIdx.x;                       // blockDim.x == MAX_BINS
    int v = 0;
    if (t < nbins) {
#pragma unroll 8
        for (int k = 0; k < HIST_BLOCKS; ++k)
            v += partial[k * MAX_BINS + t];
    }
    s[t] = v;
    __syncthreads();
    for (int off = 1; off < MAX_BINS; off <<= 1) {
        int u = (t >= off) ? s[t - off] : 0;
        __syncthreads();
        s[t] += u;
        __syncthreads();
    }
    if (t < nbins) {
        int excl = s[t] - v;
        binofs[t] = excl;
        bincur[t] = excl;
        if (t == nbins - 1) binofs[nbins] = s[t];
    }
}

// K2: partition edges into 256-node bins. 1024 threads/block: 32 waves/CU
// with unchanged chunking (write locality preserved).
__global__ void __launch_bounds__(PART_THREADS)
partition_bins(const int* __restrict__ src, const int* __restrict__ dst,
               int n_edges, int* __restrict__ bincur,
               uint32_t* __restrict__ binstream, int nbins) {
    __shared__ int cnt[MAX_BINS];
    __shared__ int base[MAX_BINS];
    const int chunk = (n_edges + gridDim.x - 1) / gridDim.x;
    const int beg = blockIdx.x * chunk;
    const int end = min(beg + chunk, n_edges);

    for (int b = threadIdx.x; b < nbins; b += blockDim.x) cnt[b] = 0;
    __syncthreads();
    for (int i = beg + threadIdx.x; i < end; i += blockDim.x)
        atomicAdd(&cnt[dst[i] >> NPB_SHIFT], 1);           // LDS atomic
    __syncthreads();
    for (int b = threadIdx.x; b < nbins; b += blockDim.x) {
        int c = cnt[b];
        base[b] = c ? atomicAdd(&bincur[b], c) : 0;        // one global atomic each
        cnt[b] = 0;                                        // becomes local cursor
    }
    __syncthreads();
    for (int i = beg + threadIdx.x; i < end; i += blockDim.x) {
        int d = dst[i];
        int s = src[i];
        int b = d >> NPB_SHIFT;
        int p = base[b] + atomicAdd(&cnt[b], 1);           // LDS atomic
        binstream[p] = ((uint32_t)s << NPB_SHIFT) | (uint32_t)(d & (NPB - 1));
    }
}

// K3: one block per bin, 1024 threads. Scan phases use first NPB lanes;
// placement/copy loops use all threads.
__global__ void __launch_bounds__(SORT_THREADS)
binsort(const uint32_t* __restrict__ binstream, const int* __restrict__ binofs,
        int nbins, uint32_t* __restrict__ sorted, int* __restrict__ offsets,
        int n_nodes) {
    __shared__ uint32_t srtd[BIN_CAP];     // 32 KB
    __shared__ int hist[NPB];
    __shared__ int sc[NPB];
    __shared__ int lcur[NPB];
    const int b = blockIdx.x;
    const int n0 = b << NPB_SHIFT;
    const int nn = min(NPB, n_nodes - n0);
    const int binstart = binofs[b];
    const int cnt = binofs[b + 1] - binstart;
    const int t = threadIdx.x;

    if (t < NPB) { hist[t] = 0; lcur[t] = 0; }
    __syncthreads();

    for (int i = t; i < cnt; i += blockDim.x)
        atomicAdd(&hist[binstream[binstart + i] & (NPB - 1)], 1);
    __syncthreads();

    // inclusive scan of hist into sc (first NPB lanes; all threads hit barriers)
    int v = 0;
    if (t < NPB) { v = hist[t]; sc[t] = v; }
    __syncthreads();
    for (int off = 1; off < NPB; off <<= 1) {
        int u = 0;
        if (t < NPB && t >= off) u = sc[t - off];
        __syncthreads();
        if (t < NPB) sc[t] += u;
        __syncthreads();
    }
    if (t < nn) offsets[n0 + t + 1] = binstart + sc[t];
    if (b == 0 && t == 0) offsets[0] = 0;
    if (t < NPB) hist[t] = sc[t] - v;      // exclusive
    __syncthreads();

    if (cnt <= BIN_CAP) {
        for (int i = t; i < cnt; i += blockDim.x) {
            uint32_t e = binstream[binstart + i];          // coalesced read
            int dl = (int)(e & (NPB - 1));
            int p = hist[dl] + atomicAdd(&lcur[dl], 1);
            srtd[p] = e >> NPB_SHIFT;                      // src id
        }
        __syncthreads();
        for (int i = t; i < cnt; i += blockDim.x)
            sorted[binstart + i] = srtd[i];                // coalesced write
    } else {
        // overflow (>BIN_CAP edges in one bin; ~impossible for random input)
        for (int i = t; i < cnt; i += blockDim.x) {
            uint32_t e = binstream[binstart + i];
            int dl = (int)(e & (NPB - 1));
            int p = binstart + hist[dl] + atomicAdd(&lcur[dl], 1);
            sorted[p] = e >> NPB_SHIFT;
        }
    }
}

// K4: one 32-lane group per node, float4 lanes, 16 edges in flight.
__global__ void __launch_bounds__(256)
aggregate_f4(const float* __restrict__ x,
             const uint32_t* __restrict__ sorted,
             const int* __restrict__ offsets,
             float* __restrict__ out, int n_nodes) {
    int tid = blockIdx.x * blockDim.x + threadIdx.x;
    int g = tid >> 5;                  // node id (32 lanes per node)
    if (g >= n_nodes) return;
    int l  = tid & 31;
    int e4 = l >> 3;                   // edge slot 0..3
    int q  = l & 7;                    // feature quad 0..7
    const float4* __restrict__ x4 = (const float4*)x;

    int beg = offsets[g];
    int end = offsets[g + 1];
    float4 acc = make_float4(0.f, 0.f, 0.f, 0.f);

    for (int i = beg; i < end; i += 16) {
#pragma unroll
        for (int k = 0; k < 4; ++k) {
            int j = i + k * 4 + e4;
            bool ok = j < end;
            uint32_t s = sorted[ok ? j : i];              // clamp: i < end here
            float4 v = x4[(size_t)s * (N_FEAT / 4) + q];  // 16B/lane gather
            float m = ok ? 1.0f : 0.0f;
            acc.x = fmaf(v.x, m, acc.x);
            acc.y = fmaf(v.y, m, acc.y);
            acc.z = fmaf(v.z, m, acc.z);
            acc.w = fmaf(v.w, m, acc.w);
        }
    }
    acc.x += __shfl_xor(acc.x, 8);  acc.y += __shfl_xor(acc.y, 8);
    acc.z += __shfl_xor(acc.z, 8);  acc.w += __shfl_xor(acc.w, 8);
    acc.x += __shfl_xor(acc.x, 16); acc.y += __shfl_xor(acc.y, 16);
    acc.z += __shfl_xor(acc.z, 16); acc.w += __shfl_xor(acc.w, 16);

    if (e4 == 0)
        ((float4*)out)[(size_t)g * (N_FEAT / 4) + q] = acc;
}

extern "C" void kernel_launch(void* const* d_in, const int* in_sizes, int n_in,
                              void* d_out, int out_size, void* d_ws, size_t ws_size,
                              hipStream_t stream) {
    const float* x   = (const float*)d_in[0];
    const int*   ei  = (const int*)d_in[1];
    float*       out = (float*)d_out;

    const int n_edges = in_sizes[1] / 2;
    const int n_nodes = in_sizes[0] / N_FEAT;
    const int* src = ei;
    const int* dst = ei + n_edges;

    const int nbins = (n_nodes + NPB - 1) >> NPB_SHIFT;

    // workspace layout
    size_t off_binstream = 0;
    size_t off_sorted    = off_binstream + (size_t)n_edges * sizeof(uint32_t);
    size_t off_offsets   = off_sorted + (size_t)n_edges * sizeof(uint32_t);
    size_t off_partial   = off_offsets + (size_t)(n_nodes + 1) * sizeof(int);
    size_t off_binofs    = off_partial + (size_t)HIST_BLOCKS * MAX_BINS * sizeof(int);
    size_t off_bincur    = off_binofs + (size_t)(nbins + 1) * sizeof(int);
    size_t ws_needed     = off_bincur + (size_t)nbins * sizeof(int);

    if (nbins > MAX_BINS || n_nodes > (1 << 23) || ws_size < ws_needed) {
        // fallback: baseline atomic scatter (correct, ~177us)
        int threads = 256;
        zero_out<<<(out_size + threads - 1) / threads, threads, 0, stream>>>(out, out_size);
        long long total = (long long)n_edges * N_FEAT;
        mp_scatter_add<<<(int)((total + threads - 1) / threads), threads, 0, stream>>>(
            x, src, dst, out, n_edges);
        return;
    }

    char* ws = (char*)d_ws;
    uint32_t* binstream = (uint32_t*)(ws + off_binstream);
    uint32_t* sorted    = (uint32_t*)(ws + off_sorted);
    int*      offsets   = (int*)(ws + off_offsets);
    int*      partial   = (int*)(ws + off_partial);
    int*      binofs    = (int*)(ws + off_binofs);
    int*      bincur    = (int*)(ws + off_bincur);

    bin_hist<<<HIST_BLOCKS, HIST_THREADS, 0, stream>>>(dst, n_edges, partial, nbins);
    bin_scan<<<1, MAX_BINS, 0, stream>>>(partial, nbins, binofs, bincur);
    partition_bins<<<PART_BLOCKS, PART_THREADS, 0, stream>>>(src, dst, n_edges, bincur, binstream, nbins);
    binsort<<<nbins, SORT_THREADS, 0, stream>>>(binstream, binofs, nbins, sorted, offsets, n_nodes);
    aggregate_f4<<<(n_nodes * 32 + 255) / 256, 256, 0, stream>>>(x, sorted, offsets, out, n_nodes);
}

// Round 12
// 76.711 us; speedup vs baseline: 2.4171x; 1.1037x over previous
//
#include <hip/hip_runtime.h>
#include <stdint.h>

#define N_FEAT 32
#define NPB_SHIFT 8                   // 256 nodes per bin
#define NPB (1 << NPB_SHIFT)
#define MAX_BINS 512
#define BIN_CAP 8192                  // LDS sort capacity; avg bin ~4096 edges
#define PART_BLOCKS 512               // 2 blocks/CU
#define PART_THREADS 1024             // 16 waves/block -> 32 waves/CU
#define HIST_BLOCKS 256
#define HIST_THREADS 1024
#define FUSE_THREADS 1024

// ---------- fallback path (baseline, known-correct, ~177us) ----------
__global__ void zero_out(float* __restrict__ out, int n) {
    int i = blockIdx.x * blockDim.x + threadIdx.x;
    if (i < n) out[i] = 0.0f;
}

__global__ void mp_scatter_add(const float* __restrict__ x,
                               const int* __restrict__ src,
                               const int* __restrict__ dst,
                               float* __restrict__ out,
                               int n_edges) {
    long long tid = (long long)blockIdx.x * blockDim.x + threadIdx.x;
    long long total = (long long)n_edges * N_FEAT;
    if (tid >= total) return;
    int e = (int)(tid >> 5);
    int f = (int)(tid & 31);
    atomicAdd(&out[(long long)dst[e] * N_FEAT + f],
              x[(long long)src[e] * N_FEAT + f]);
}

// ---------- fast path ----------
// R12: binsort and aggregate are FUSED — the sorted edge list lives only in
// LDS (srtd), per-node offsets only in LDS (hist/sc). `sorted`/`offsets`
// global arrays deleted (~14MB traffic + 1 launch).

// K0: per-block partial bin histogram (plain stores; no memset needed).
__global__ void __launch_bounds__(HIST_THREADS)
bin_hist(const int* __restrict__ dst, int n_edges,
         int* __restrict__ partial, int nbins) {
    __shared__ int lh[MAX_BINS];
    for (int j = threadIdx.x; j < nbins; j += blockDim.x) lh[j] = 0;
    __syncthreads();
    int stride = gridDim.x * blockDim.x;
    for (int i = blockIdx.x * blockDim.x + threadIdx.x; i < n_edges; i += stride)
        atomicAdd(&lh[__builtin_nontemporal_load(&dst[i]) >> NPB_SHIFT], 1);
    __syncthreads();
    for (int j = threadIdx.x; j < nbins; j += blockDim.x)
        partial[blockIdx.x * MAX_BINS + j] = lh[j];        // coalesced store
}

// K1: reduce partials + exclusive scan -> binofs, bincur.
__global__ void bin_scan(const int* __restrict__ partial, int nbins,
                         int* __restrict__ binofs, int* __restrict__ bincur) {
    __shared__ int s[MAX_BINS];
    int t = threadIdx.x;                       // blockDim.x == MAX_BINS
    int v = 0;
    if (t < nbins) {
#pragma unroll 8
        for (int k = 0; k < HIST_BLOCKS; ++k)
            v += partial[k * MAX_BINS + t];
    }
    s[t] = v;
    __syncthreads();
    for (int off = 1; off < MAX_BINS; off <<= 1) {
        int u = (t >= off) ? s[t - off] : 0;
        __syncthreads();
        s[t] += u;
        __syncthreads();
    }
    if (t < nbins) {
        int excl = s[t] - v;
        binofs[t] = excl;
        bincur[t] = excl;
        if (t == nbins - 1) binofs[nbins] = s[t];
    }
}

// K2: partition edges into 256-node bins (unchanged from R11).
__global__ void __launch_bounds__(PART_THREADS)
partition_bins(const int* __restrict__ src, const int* __restrict__ dst,
               int n_edges, int* __restrict__ bincur,
               uint32_t* __restrict__ binstream, int nbins) {
    __shared__ int cnt[MAX_BINS];
    __shared__ int base[MAX_BINS];
    const int chunk = (n_edges + gridDim.x - 1) / gridDim.x;
    const int beg = blockIdx.x * chunk;
    const int end = min(beg + chunk, n_edges);

    for (int b = threadIdx.x; b < nbins; b += blockDim.x) cnt[b] = 0;
    __syncthreads();
    for (int i = beg + threadIdx.x; i < end; i += blockDim.x)
        atomicAdd(&cnt[dst[i] >> NPB_SHIFT], 1);           // LDS atomic
    __syncthreads();
    for (int b = threadIdx.x; b < nbins; b += blockDim.x) {
        int c = cnt[b];
        base[b] = c ? atomicAdd(&bincur[b], c) : 0;        // one global atomic each
        cnt[b] = 0;                                        // becomes local cursor
    }
    __syncthreads();
    for (int i = beg + threadIdx.x; i < end; i += blockDim.x) {
        int d = dst[i];
        int s = src[i];
        int b = d >> NPB_SHIFT;
        int p = base[b] + atomicAdd(&cnt[b], 1);           // LDS atomic
        binstream[p] = ((uint32_t)s << NPB_SHIFT) | (uint32_t)(d & (NPB - 1));
    }
}

// K3 (FUSED): one block per bin. Sort the bin's edges into LDS at final
// rank, then aggregate directly: 32-lane group g owns nodes {g, g+32, ...};
// per node: 4 edge-slots x 8 float4 lanes = 16 rows in flight; shfl reduce;
// one coalesced 128B row write per node (zeros for degree-0 nodes).
__global__ void __launch_bounds__(FUSE_THREADS)
binsort_aggregate(const uint32_t* __restrict__ binstream,
                  const int* __restrict__ binofs,
                  const float* __restrict__ x,
                  float* __restrict__ out, int n_nodes) {
    __shared__ uint32_t srtd[BIN_CAP];     // 32 KB
    __shared__ int hist[NPB];              // exclusive per-node start
    __shared__ int sc[NPB];                // inclusive per-node end
    __shared__ int lcur[NPB];
    const int b = blockIdx.x;
    const int n0 = b << NPB_SHIFT;
    const int nn = min(NPB, n_nodes - n0);
    const int binstart = binofs[b];
    const int cnt = binofs[b + 1] - binstart;
    const int t = threadIdx.x;
    const int g  = t >> 5;                 // group 0..31 (one node at a time)
    const int l  = t & 31;
    const int e4 = l >> 3;                 // edge slot 0..3
    const int q  = l & 7;                  // feature quad 0..7
    const float4* __restrict__ x4 = (const float4*)x;
    float4* __restrict__ out4 = (float4*)out;

    if (cnt <= BIN_CAP) {
        if (t < NPB) { hist[t] = 0; lcur[t] = 0; }
        __syncthreads();
        for (int i = t; i < cnt; i += FUSE_THREADS)
            atomicAdd(&hist[binstream[binstart + i] & (NPB - 1)], 1);
        __syncthreads();
        int v = 0;
        if (t < NPB) { v = hist[t]; sc[t] = v; }
        __syncthreads();
        for (int off = 1; off < NPB; off <<= 1) {
            int u = 0;
            if (t < NPB && t >= off) u = sc[t - off];
            __syncthreads();
            if (t < NPB) sc[t] += u;
            __syncthreads();
        }
        if (t < NPB) hist[t] = sc[t] - v;  // exclusive start
        __syncthreads();
        for (int i = t; i < cnt; i += FUSE_THREADS) {
            uint32_t e = binstream[binstart + i];          // coalesced read
            int dl = (int)(e & (NPB - 1));
            int p = hist[dl] + atomicAdd(&lcur[dl], 1);
            srtd[p] = e >> NPB_SHIFT;                      // src id
        }
        __syncthreads();

        for (int dl = g; dl < nn; dl += 32) {
            int beg = hist[dl];
            int end = sc[dl];
            float4 acc = make_float4(0.f, 0.f, 0.f, 0.f);
            for (int i = beg; i < end; i += 16) {
#pragma unroll
                for (int k = 0; k < 4; ++k) {
                    int j = i + k * 4 + e4;
                    bool ok = j < end;
                    uint32_t s = srtd[ok ? j : i];         // LDS broadcast read
                    float4 vv = x4[(size_t)s * (N_FEAT / 4) + q];
                    float m = ok ? 1.0f : 0.0f;
                    acc.x = fmaf(vv.x, m, acc.x);
                    acc.y = fmaf(vv.y, m, acc.y);
                    acc.z = fmaf(vv.z, m, acc.z);
                    acc.w = fmaf(vv.w, m, acc.w);
                }
            }
            acc.x += __shfl_xor(acc.x, 8);  acc.y += __shfl_xor(acc.y, 8);
            acc.z += __shfl_xor(acc.z, 8);  acc.w += __shfl_xor(acc.w, 8);
            acc.x += __shfl_xor(acc.x, 16); acc.y += __shfl_xor(acc.y, 16);
            acc.z += __shfl_xor(acc.z, 16); acc.w += __shfl_xor(acc.w, 16);
            if (e4 == 0)
                out4[(size_t)(n0 + dl) * (N_FEAT / 4) + q] = acc;
        }
    } else {
        // overflow (>BIN_CAP edges in one bin; ~impossible for random input):
        // predicate-scan the bin segment from global memory per owned node.
        for (int dl = g; dl < nn; dl += 32) {
            float4 acc = make_float4(0.f, 0.f, 0.f, 0.f);
            for (int i = 0; i < cnt; i += 4) {
                int j = i + e4;
                bool ok = j < cnt;
                uint32_t e = binstream[binstart + (ok ? j : i)];
                bool match = ok && ((int)(e & (NPB - 1)) == dl);
                float4 vv = x4[(size_t)(e >> NPB_SHIFT) * (N_FEAT / 4) + q];
                float m = match ? 1.0f : 0.0f;
                acc.x = fmaf(vv.x, m, acc.x);
                acc.y = fmaf(vv.y, m, acc.y);
                acc.z = fmaf(vv.z, m, acc.z);
                acc.w = fmaf(vv.w, m, acc.w);
            }
            acc.x += __shfl_xor(acc.x, 8);  acc.y += __shfl_xor(acc.y, 8);
            acc.z += __shfl_xor(acc.z, 8);  acc.w += __shfl_xor(acc.w, 8);
            acc.x += __shfl_xor(acc.x, 16); acc.y += __shfl_xor(acc.y, 16);
            acc.z += __shfl_xor(acc.z, 16); acc.w += __shfl_xor(acc.w, 16);
            if (e4 == 0)
                out4[(size_t)(n0 + dl) * (N_FEAT / 4) + q] = acc;
        }
    }
}

extern "C" void kernel_launch(void* const* d_in, const int* in_sizes, int n_in,
                              void* d_out, int out_size, void* d_ws, size_t ws_size,
                              hipStream_t stream) {
    const float* x   = (const float*)d_in[0];
    const int*   ei  = (const int*)d_in[1];
    float*       out = (float*)d_out;

    const int n_edges = in_sizes[1] / 2;
    const int n_nodes = in_sizes[0] / N_FEAT;
    const int* src = ei;
    const int* dst = ei + n_edges;

    const int nbins = (n_nodes + NPB - 1) >> NPB_SHIFT;

    // workspace layout
    size_t off_binstream = 0;
    size_t off_partial   = off_binstream + (size_t)n_edges * sizeof(uint32_t);
    size_t off_binofs    = off_partial + (size_t)HIST_BLOCKS * MAX_BINS * sizeof(int);
    size_t off_bincur    = off_binofs + (size_t)(nbins + 1) * sizeof(int);
    size_t ws_needed     = off_bincur + (size_t)nbins * sizeof(int);

    if (nbins > MAX_BINS || n_nodes > (1 << 23) || ws_size < ws_needed) {
        // fallback: baseline atomic scatter (correct, ~177us)
        int threads = 256;
        zero_out<<<(out_size + threads - 1) / threads, threads, 0, stream>>>(out, out_size);
        long long total = (long long)n_edges * N_FEAT;
        mp_scatter_add<<<(int)((total + threads - 1) / threads), threads, 0, stream>>>(
            x, src, dst, out, n_edges);
        return;
    }

    char* ws = (char*)d_ws;
    uint32_t* binstream = (uint32_t*)(ws + off_binstream);
    int*      partial   = (int*)(ws + off_partial);
    int*      binofs    = (int*)(ws + off_binofs);
    int*      bincur    = (int*)(ws + off_bincur);

    bin_hist<<<HIST_BLOCKS, HIST_THREADS, 0, stream>>>(dst, n_edges, partial, nbins);
    bin_scan<<<1, MAX_BINS, 0, stream>>>(partial, nbins, binofs, bincur);
    partition_bins<<<PART_BLOCKS, PART_THREADS, 0, stream>>>(src, dst, n_edges, bincur, binstream, nbins);
    binsort_aggregate<<<nbins, FUSE_THREADS, 0, stream>>>(binstream, binofs, x, out, n_nodes);
}

// Round 13
// 62.852 us; speedup vs baseline: 2.9501x; 1.2205x over previous
//
#include <hip/hip_runtime.h>
#include <stdint.h>

#define N_FEAT 32
#define NPB_SHIFT 8                   // 256 nodes per bin
#define NPB (1 << NPB_SHIFT)
#define MAX_BINS 512
#define BINSLOT 8192                  // fixed binstream slots per bin (avg load ~4096)
#define OVF_CAP 65536                 // overflow safety net (unused for this input)
#define PART_THREADS 1024
#define PART_CHUNK 3072               // edges per partition block (LDS-cached)
#define FUSE_THREADS 1024

// ---------- fallback path (baseline, known-correct, ~177us) ----------
__global__ void zero_out(float* __restrict__ out, int n) {
    int i = blockIdx.x * blockDim.x + threadIdx.x;
    if (i < n) out[i] = 0.0f;
}

__global__ void mp_scatter_add(const float* __restrict__ x,
                               const int* __restrict__ src,
                               const int* __restrict__ dst,
                               float* __restrict__ out,
                               int n_edges) {
    long long tid = (long long)blockIdx.x * blockDim.x + threadIdx.x;
    long long total = (long long)n_edges * N_FEAT;
    if (tid >= total) return;
    int e = (int)(tid >> 5);
    int f = (int)(tid & 31);
    atomicAdd(&out[(long long)dst[e] * N_FEAT + f],
              x[(long long)src[e] * N_FEAT + f]);
}

// ---------- fast path ----------
// R13: fixed-capacity bins. binstream[b*BINSLOT..] is bin b's segment;
// partition reserves with one atomic per (block,bin) on bincur (init'd by
// init_bins each call). bin_hist/bin_scan deleted. Overflow edges (never for
// this input) go to a small list merged by the fused kernel before stores.

// K0: init per-bin cursors + overflow counter (ws is poisoned; must re-init).
__global__ void init_bins(int* __restrict__ bincur, int nbins,
                          int* __restrict__ ovf_cnt) {
    int t = blockIdx.x * blockDim.x + threadIdx.x;
    if (t < nbins) bincur[t] = t * BINSLOT;
    if (t == nbins) *ovf_cnt = 0;
}

// K1: partition edges into fixed-capacity bins. Chunk cached in LDS during
// the count pass so src/dst are read from HBM exactly once.
__global__ void __launch_bounds__(PART_THREADS)
partition_bins(const int* __restrict__ src, const int* __restrict__ dst,
               int n_edges, int* __restrict__ bincur,
               uint32_t* __restrict__ binstream,
               uint32_t* __restrict__ ovf_src, uint32_t* __restrict__ ovf_dst,
               int* __restrict__ ovf_cnt, int nbins) {
    __shared__ uint32_t epack[PART_CHUNK];   // (src<<8)|dst_local
    __shared__ uint16_t ebin[PART_CHUNK];    // bin id
    __shared__ int cnt[MAX_BINS];
    __shared__ int base[MAX_BINS];
    const int beg = blockIdx.x * PART_CHUNK;
    const int end = min(beg + PART_CHUNK, n_edges);
    const int m = end - beg;

    for (int b = threadIdx.x; b < nbins; b += blockDim.x) cnt[b] = 0;
    __syncthreads();
    for (int i = threadIdx.x; i < m; i += blockDim.x) {
        int d = dst[beg + i];
        int s = src[beg + i];
        int b = d >> NPB_SHIFT;
        epack[i] = ((uint32_t)s << NPB_SHIFT) | (uint32_t)(d & (NPB - 1));
        ebin[i]  = (uint16_t)b;
        atomicAdd(&cnt[b], 1);               // LDS atomic
    }
    __syncthreads();
    for (int b = threadIdx.x; b < nbins; b += blockDim.x) {
        int c = cnt[b];
        base[b] = c ? atomicAdd(&bincur[b], c) : 0;   // one global atomic each
        cnt[b] = 0;                                   // becomes local cursor
    }
    __syncthreads();
    for (int i = threadIdx.x; i < m; i += blockDim.x) {
        int b = ebin[i];
        uint32_t e = epack[i];
        int p = base[b] + atomicAdd(&cnt[b], 1);      // LDS atomic
        if (p < (b + 1) * BINSLOT) {
            binstream[p] = e;                         // block-private segment
        } else {                                      // overflow net (never hit here)
            int o = atomicAdd(ovf_cnt, 1);
            if (o < OVF_CAP) {
                ovf_src[o] = e >> NPB_SHIFT;
                ovf_dst[o] = ((uint32_t)b << NPB_SHIFT) | (e & (NPB - 1));
            }
        }
    }
}

// K2 (FUSED): one block per bin. LDS rank-sort of the bin's edges, then
// per-node register aggregation: 32-lane group = 4 edge-slots x 8 float4
// lanes (16 rows in flight), shfl reduce, one coalesced 128B row store.
__global__ void __launch_bounds__(FUSE_THREADS)
binsort_aggregate(const uint32_t* __restrict__ binstream,
                  const int* __restrict__ bincur,
                  const uint32_t* __restrict__ ovf_src,
                  const uint32_t* __restrict__ ovf_dst,
                  const int* __restrict__ ovf_cnt,
                  const float* __restrict__ x,
                  float* __restrict__ out, int n_nodes) {
    __shared__ uint32_t srtd[BINSLOT];     // 32 KB
    __shared__ int hist[NPB];              // exclusive per-node start
    __shared__ int sc[NPB];                // inclusive per-node end
    __shared__ int lcur[NPB];
    const int b = blockIdx.x;
    const int n0 = b << NPB_SHIFT;
    const int nn = min(NPB, n_nodes - n0);
    const int binstart = b * BINSLOT;
    const int cnt = min(bincur[b] - binstart, BINSLOT);
    const int novf = *ovf_cnt;             // 0 in practice
    const int t = threadIdx.x;
    const int g  = t >> 5;                 // group 0..31
    const int l  = t & 31;
    const int e4 = l >> 3;                 // edge slot 0..3
    const int q  = l & 7;                  // feature quad 0..7
    const float4* __restrict__ x4 = (const float4*)x;
    float4* __restrict__ out4 = (float4*)out;

    if (t < NPB) { hist[t] = 0; lcur[t] = 0; }
    __syncthreads();
    for (int i = t; i < cnt; i += FUSE_THREADS)
        atomicAdd(&hist[binstream[binstart + i] & (NPB - 1)], 1);
    __syncthreads();
    int v = 0;
    if (t < NPB) { v = hist[t]; sc[t] = v; }
    __syncthreads();
    for (int off = 1; off < NPB; off <<= 1) {
        int u = 0;
        if (t < NPB && t >= off) u = sc[t - off];
        __syncthreads();
        if (t < NPB) sc[t] += u;
        __syncthreads();
    }
    if (t < NPB) hist[t] = sc[t] - v;      // exclusive start
    __syncthreads();
    for (int i = t; i < cnt; i += FUSE_THREADS) {
        uint32_t e = binstream[binstart + i];          // coalesced read
        int dl = (int)(e & (NPB - 1));
        int p = hist[dl] + atomicAdd(&lcur[dl], 1);
        srtd[p] = e >> NPB_SHIFT;                      // src id
    }
    __syncthreads();

    for (int dl = g; dl < nn; dl += 32) {
        int beg = hist[dl];
        int end = sc[dl];
        float4 acc = make_float4(0.f, 0.f, 0.f, 0.f);
        for (int i = beg; i < end; i += 16) {
#pragma unroll
            for (int k = 0; k < 4; ++k) {
                int j = i + k * 4 + e4;
                bool ok = j < end;
                uint32_t s = srtd[ok ? j : i];         // LDS broadcast read
                float4 vv = x4[(size_t)s * (N_FEAT / 4) + q];
                float m = ok ? 1.0f : 0.0f;
                acc.x = fmaf(vv.x, m, acc.x);
                acc.y = fmaf(vv.y, m, acc.y);
                acc.z = fmaf(vv.z, m, acc.z);
                acc.w = fmaf(vv.w, m, acc.w);
            }
        }
        acc.x += __shfl_xor(acc.x, 8);  acc.y += __shfl_xor(acc.y, 8);
        acc.z += __shfl_xor(acc.z, 8);  acc.w += __shfl_xor(acc.w, 8);
        acc.x += __shfl_xor(acc.x, 16); acc.y += __shfl_xor(acc.y, 16);
        acc.z += __shfl_xor(acc.z, 16); acc.w += __shfl_xor(acc.w, 16);
        if (e4 == 0) {
            // overflow merge (novf == 0 normally; loop skipped)
            for (int i = 0; i < novf; ++i) {
                uint32_t od = ovf_dst[i];
                if ((int)(od >> NPB_SHIFT) == b && (int)(od & (NPB - 1)) == dl) {
                    float4 vv = x4[(size_t)ovf_src[i] * (N_FEAT / 4) + q];
                    acc.x += vv.x; acc.y += vv.y; acc.z += vv.z; acc.w += vv.w;
                }
            }
            out4[(size_t)(n0 + dl) * (N_FEAT / 4) + q] = acc;
        }
    }
}

extern "C" void kernel_launch(void* const* d_in, const int* in_sizes, int n_in,
                              void* d_out, int out_size, void* d_ws, size_t ws_size,
                              hipStream_t stream) {
    const float* x   = (const float*)d_in[0];
    const int*   ei  = (const int*)d_in[1];
    float*       out = (float*)d_out;

    const int n_edges = in_sizes[1] / 2;
    const int n_nodes = in_sizes[0] / N_FEAT;
    const int* src = ei;
    const int* dst = ei + n_edges;

    const int nbins = (n_nodes + NPB - 1) >> NPB_SHIFT;

    // workspace layout
    size_t off_binstream = 0;
    size_t off_ovf_src   = off_binstream + (size_t)nbins * BINSLOT * sizeof(uint32_t);
    size_t off_ovf_dst   = off_ovf_src + (size_t)OVF_CAP * sizeof(uint32_t);
    size_t off_bincur    = off_ovf_dst + (size_t)OVF_CAP * sizeof(uint32_t);
    size_t off_ovf_cnt   = off_bincur + (size_t)nbins * sizeof(int);
    size_t ws_needed     = off_ovf_cnt + sizeof(int);

    if (nbins > MAX_BINS || n_nodes > (1 << 23) || ws_size < ws_needed) {
        // fallback: baseline atomic scatter (correct, ~177us)
        int threads = 256;
        zero_out<<<(out_size + threads - 1) / threads, threads, 0, stream>>>(out, out_size);
        long long total = (long long)n_edges * N_FEAT;
        mp_scatter_add<<<(int)((total + threads - 1) / threads), threads, 0, stream>>>(
            x, src, dst, out, n_edges);
        return;
    }

    char* ws = (char*)d_ws;
    uint32_t* binstream = (uint32_t*)(ws + off_binstream);
    uint32_t* ovf_src   = (uint32_t*)(ws + off_ovf_src);
    uint32_t* ovf_dst   = (uint32_t*)(ws + off_ovf_dst);
    int*      bincur    = (int*)(ws + off_bincur);
    int*      ovf_cnt   = (int*)(ws + off_ovf_cnt);

    init_bins<<<(nbins + 256) / 256, 256, 0, stream>>>(bincur, nbins, ovf_cnt);

    const int part_blocks = (n_edges + PART_CHUNK - 1) / PART_CHUNK;
    partition_bins<<<part_blocks, PART_THREADS, 0, stream>>>(
        src, dst, n_edges, bincur, binstream, ovf_src, ovf_dst, ovf_cnt, nbins);

    binsort_aggregate<<<nbins, FUSE_THREADS, 0, stream>>>(
        binstream, bincur, ovf_src, ovf_dst, ovf_cnt, x, out, n_nodes);
}